// Round 8
// baseline (510.544 us; speedup 1.0000x reference)
//
#include <hip/hip_runtime.h>
#include <math.h>

#define NN 6000
#define NSUB 4500
#define BB 8
#define DD 192
#define GD 40
#define KTOP 10
#define NLAY 3
#define ROWS (BB*NN)          // 48000
#define NEDGE (NN*(KTOP+1))   // 66000
#define WMAT (DD*DD)          // 36864
#define NSTRIP 8
#define SCOLS 750             // cols per strip (8*750 = 6000)
#define NTILE 12              // ceil(750/64)
#define RCAP 6016             // padded row capacity for partials
#define KP 96                 // padded K for f16 tables (= 24 uint2 chunks of 4 f16)
#define SP2 100               // LDS row pitch in f16 (50 dw, 16-bank spread; rows 8B-aligned)

typedef unsigned short u16;
typedef unsigned int u32;
typedef __attribute__((ext_vector_type(8))) short bf16x8;
typedef __attribute__((ext_vector_type(8))) _Float16 f16x8;
typedef __attribute__((ext_vector_type(4))) float f32x4;

__device__ __forceinline__ u16 f2b(float x){
  u32 u = __float_as_uint(x);
  u32 r = (u + 0x7fffu + ((u >> 16) & 1u)) >> 16;
  return (u16)r;
}
__device__ __forceinline__ float b2f(u16 h){
  u32 u = ((u32)h) << 16; return __uint_as_float(u);
}
// order-preserving monotone float->uint key
__device__ __forceinline__ u32 fkey(float f){
  u32 b = __float_as_uint(f);
  return (b & 0x80000000u) ? ~b : (b | 0x80000000u);
}
__device__ __forceinline__ void wr_hl(u16* __restrict__ H, u16* __restrict__ L, size_t off, float x){
  _Float16 hx = (_Float16)x;
  H[off] = __builtin_bit_cast(u16, hx);
  _Float16 lx = (_Float16)(x - (float)hx);
  L[off] = __builtin_bit_cast(u16, lx);
}
// load 8 consecutive f16 as two 8B chunks (8B-aligned)
__device__ __forceinline__ f16x8 ldfrag(const u16* p){
  union { f16x8 v; double d[2]; } u;
  const double* q = (const double*)p;
  u.d[0] = q[0]; u.d[1] = q[1];
  return u.v;
}

// ---------------- graph-constructor prep: f16 hi/lo tables ----------------
// U[i] = [0.5*nv1_i, 0.5*nv2_i, 0pad], V[j] = [nv2_j, nv1_j, 0pad]  (96 f16 each, hi+lo)
__global__ void k_prep_uv(const float* __restrict__ emb1, const float* __restrict__ emb2,
                          const float* __restrict__ w1, const float* __restrict__ b1,
                          const float* __restrict__ w2, const float* __restrict__ b2,
                          u16* __restrict__ Uh, u16* __restrict__ Ul,
                          u16* __restrict__ Vh, u16* __restrict__ Vl){
  int id = blockIdx.x*blockDim.x + threadIdx.x;
  if (id >= NN*GD) return;
  int i = id / GD, g = id % GD;
  float s1 = b1[g], s2 = b2[g];
  for (int k = 0; k < GD; k++){
    s1 += emb1[i*GD+k]*w1[k*GD+g];
    s2 += emb2[i*GD+k]*w2[k*GD+g];
  }
  float n1 = tanhf(3.0f*s1), n2 = tanhf(3.0f*s2);
  size_t base = (size_t)i*KP;
  wr_hl(Uh, Ul, base + g,      0.5f*n1);
  wr_hl(Uh, Ul, base + 40 + g, 0.5f*n2);
  wr_hl(Vh, Vl, base + g,      n2);
  wr_hl(Vh, Vl, base + 40 + g, n1);
  if (g < 16){
    Uh[base+80+g] = 0; Ul[base+80+g] = 0;
    Vh[base+80+g] = 0; Vl[base+80+g] = 0;
  }
}

// ---------------- fused score (MFMA f16-split) + register top-k ----------------
// Block: 64 rows (wave w owns row 16w+ln) x 750-col strip, 12 tiles of 64 cols.
// Score tile computed transposed: mfma(A=V-frag, B=U-frag) -> lane holds one row.
// Staging invariant: KP=96 f16 per row = 24 uint2 chunks (4 f16 each). Loop bound 64*24.
__global__ __launch_bounds__(256, 3) void k_scoretopk(
                          const u16* __restrict__ Uh, const u16* __restrict__ Ul,
                          const u16* __restrict__ Vh, const u16* __restrict__ Vl,
                          float* __restrict__ ptv, int* __restrict__ ptc){
  __shared__ u16 Us[2*64*SP2];      // hi | lo  (25600 B)
  __shared__ u16 Vs[2*64*SP2];      // 25600 B  -> total 51456 B => 3 blocks/CU
  __shared__ u32 rowthr[64];
  u16* Ushi = Us;        u16* Uslo = Us + 64*SP2;
  u16* Vshi = Vs;        u16* Vslo = Vs + 64*SP2;

  const int tid = threadIdx.x, lane = tid & 63, wave = tid >> 6;
  const int q = lane >> 4, ln = lane & 15;
  const int r0 = blockIdx.x*64;
  const int y  = blockIdx.y;
  const int cstart = y*SCOLS, cend = cstart + SCOLS;
  const float NINF = -__builtin_inff();
  const int lrow = wave*16 + ln;

  // ---- stage U rows once (24 x uint2 per row per plane = full 96 f16) ----
  for (int idx = tid; idx < 64*24; idx += 256){
    int r = idx/24, c8 = idx%24;               // c8: 8B chunk (4 f16)
    int gr = r0 + r; if (gr > NN-1) gr = NN-1;
    *(uint2*)&Ushi[r*SP2 + c8*4] = *(const uint2*)&Uh[(size_t)gr*KP + c8*4];
    *(uint2*)&Uslo[r*SP2 + c8*4] = *(const uint2*)&Ul[(size_t)gr*KP + c8*4];
  }
  if (tid < 64) rowthr[tid] = 0u;
  __syncthreads();

  // ---- preload U fragments (rows fixed per lane) into registers ----
  f16x8 Uhf[3], Ulf[3];
  #pragma unroll
  for (int ks = 0; ks < 3; ks++){
    Uhf[ks] = ldfrag(&Ushi[lrow*SP2 + ks*32 + q*8]);
    Ulf[ks] = ldfrag(&Uslo[lrow*SP2 + ks*32 + q*8]);
  }

  float tv[10]; int ti[10];
  #pragma unroll
  for (int s = 0; s < 10; s++){ tv[s] = NINF; ti[s] = NN; }

  for (int t = 0; t < NTILE; t++){
    int cb = cstart + t*64;
    __syncthreads();   // prior tile's V-frag reads complete
    for (int idx = tid; idx < 64*24; idx += 256){
      int r = idx/24, c8 = idx%24;
      int gc = cb + r; if (gc > NN-1) gc = NN-1;
      *(uint2*)&Vshi[r*SP2 + c8*4] = *(const uint2*)&Vh[(size_t)gc*KP + c8*4];
      *(uint2*)&Vslo[r*SP2 + c8*4] = *(const uint2*)&Vl[(size_t)gc*KP + c8*4];
    }
    __syncthreads();

    // ---- batch-prefetch ALL V fragments, then MFMA sweep ----
    f16x8 vhf[4][3], vlf[4][3];
    #pragma unroll
    for (int ch = 0; ch < 4; ch++)
      #pragma unroll
      for (int ks = 0; ks < 3; ks++){
        vhf[ch][ks] = ldfrag(&Vshi[(ch*16 + ln)*SP2 + ks*32 + q*8]);
        vlf[ch][ks] = ldfrag(&Vslo[(ch*16 + ln)*SP2 + ks*32 + q*8]);
      }

    f32x4 acc[4];
    #pragma unroll
    for (int ch = 0; ch < 4; ch++) acc[ch] = (f32x4){0.f,0.f,0.f,0.f};
    #pragma unroll
    for (int ks = 0; ks < 3; ks++){
      #pragma unroll
      for (int ch = 0; ch < 4; ch++){
        acc[ch] = __builtin_amdgcn_mfma_f32_16x16x32_f16(vhf[ch][ks], Uhf[ks], acc[ch], 0, 0, 0);
        acc[ch] = __builtin_amdgcn_mfma_f32_16x16x32_f16(vhf[ch][ks], Ulf[ks], acc[ch], 0, 0, 0);
        acc[ch] = __builtin_amdgcn_mfma_f32_16x16x32_f16(vlf[ch][ks], Uhf[ks], acc[ch], 0, 0, 0);
      }
    }

    // ---- insert with two-level max-prune: lane's 16 scores all belong to row lrow ----
    u32 Treg = rowthr[lrow];
    float m01 = fmaxf(fmaxf(acc[0][0], acc[0][1]), fmaxf(acc[0][2], acc[0][3]));
    float m23 = fmaxf(fmaxf(acc[1][0], acc[1][1]), fmaxf(acc[1][2], acc[1][3]));
    float m45 = fmaxf(fmaxf(acc[2][0], acc[2][1]), fmaxf(acc[2][2], acc[2][3]));
    float m67 = fmaxf(fmaxf(acc[3][0], acc[3][1]), fmaxf(acc[3][2], acc[3][3]));
    float mall = fmaxf(fmaxf(m01, m23), fmaxf(m45, m67));
    if (mall > tv[9] && fkey(mall) > Treg){
      float mms[4] = {m01, m23, m45, m67};
      #pragma unroll
      for (int ch = 0; ch < 4; ch++){
        if (mms[ch] > tv[9] && fkey(mms[ch]) > Treg){
          #pragma unroll
          for (int rg = 0; rg < 4; rg++){
            int j = cb + ch*16 + q*4 + rg;
            float v = acc[ch][rg];
            u32 uk = fkey(v);
            if (j < cend && uk > Treg && v > tv[9]){
              bool b[9];
              #pragma unroll
              for (int k = 0; k < 9; k++) b[k] = v > tv[k];
              #pragma unroll
              for (int k = 9; k >= 1; k--){
                bool bh = b[k-1];
                bool bk = (k == 9) ? true : b[k];
                tv[k] = bh ? tv[k-1] : (bk ? v : tv[k]);
                ti[k] = bh ? ti[k-1] : (bk ? j : ti[k]);
              }
              if (b[0]){ tv[0] = v; ti[0] = j; }
              u32 k9 = fkey(tv[9]);
              if (k9 > Treg) Treg = k9;
              atomicMax(&rowthr[lrow], k9);
            }
          }
        }
      }
    }
  }

  // ---- per-block merge of the 4 quad lists per row (overlay on Us) ----
  __syncthreads();
  float* candv = (float*)Us;                   // 64*41 floats
  int*   candi = (int*)((u32*)Us + 64*41);     // 64*41 ints (20992 B <= 25600 B)
  #pragma unroll
  for (int s = 0; s < 10; s++){
    candv[lrow*41 + q*10 + s] = tv[s];
    candi[lrow*41 + q*10 + s] = ti[s];
  }
  __syncthreads();
  if (tid < 64 && r0 + tid < NN){
    int row = tid;
    u32 P = 0;  // 4 x 8-bit pointers
    for (int s = 0; s < 10; s++){
      float bv = NINF; int bi = NN; int by = 0;
      #pragma unroll
      for (int g = 0; g < 4; g++){
        u32 pg = (P >> (8*g)) & 255u;
        u32 pc = pg < 9u ? pg : 9u;
        float v = candv[row*41 + g*10 + pc];
        int  jj = candi[row*41 + g*10 + pc];
        if (pg >= 10u){ v = NINF; jj = NN; }
        if (v > bv || (v == bv && jj < bi)){ bv = v; bi = jj; by = g; }
      }
      P += (1u << (8*by));
      size_t o = ((size_t)y*RCAP + r0 + row)*10 + s;
      ptv[o] = bv; ptc[o] = bi;
    }
  }
}

// ---------------- merge 8 strip partials -> final topk + softplus + dis ----------------
__global__ void k_mergetopk(const float* __restrict__ ptv, const int* __restrict__ ptc,
                            int* __restrict__ topcols, float* __restrict__ topvals,
                            float* __restrict__ dis){
  int r = blockIdx.x*blockDim.x + threadIdx.x;
  if (r >= NN) return;
  const float NINF = -__builtin_inff();
  unsigned long long P = 0;  // 8 x 8-bit pointers
  float d = 1.0f;
  for (int s = 0; s < 10; s++){
    float bv = NINF; int bi = NN; int by = 0;
    #pragma unroll
    for (int g = 0; g < 8; g++){
      u32 pg = (u32)((P >> (8*g)) & 255u);
      u32 pc = pg < 9u ? pg : 9u;
      size_t o = ((size_t)g*RCAP + r)*10 + pc;
      float v = ptv[o]; int jj = ptc[o];
      if (pg >= 10u){ v = NINF; jj = NN; }
      if (v > bv || (v == bv && jj < bi)){ bv = v; bi = jj; by = g; }
    }
    P += (1ull << (8*by));
    float sp = (bv > 20.f) ? bv : log1pf(expf(bv));
    float a = sp - 0.5f; if (a < 0.f) a = 0.f;
    topvals[r*KTOP + s] = a; topcols[r*KTOP + s] = bi;
    d += a;
  }
  dis[r] = rsqrtf(d);
}

// ---------------- CSR (transpose graph) build ----------------
__global__ void k_count(const int* __restrict__ topcols, int* __restrict__ counts){
  int id = blockIdx.x*blockDim.x + threadIdx.x;
  if (id >= NEDGE) return;
  int n = id / (KTOP+1), e = id % (KTOP+1);
  int m = (e < KTOP) ? topcols[n*KTOP+e] : n;
  if ((unsigned)m >= NN) m = n;   // sentinel safety
  atomicAdd(&counts[m], 1);
}

__global__ __launch_bounds__(1024) void k_scan(const int* __restrict__ counts,
                                               int* __restrict__ rowptr, int* __restrict__ cursor){
  __shared__ int part[1024];
  int t = threadIdx.x;
  int local[6];
  int s = 0, base = t*6;
  for (int q = 0; q < 6; q++){
    int i = base + q; int c = (i < NN) ? counts[i] : 0;
    local[q] = s; s += c;
  }
  part[t] = s; __syncthreads();
  for (int off = 1; off < 1024; off <<= 1){
    int v = (t >= off) ? part[t-off] : 0;
    __syncthreads();
    part[t] += v;
    __syncthreads();
  }
  int excl = (t > 0) ? part[t-1] : 0;
  for (int q = 0; q < 6; q++){
    int i = base + q;
    if (i < NN){ int p = excl + local[q]; rowptr[i] = p; cursor[i] = p; }
  }
  if (t == 1023) rowptr[NN] = part[1023];
}

__global__ void k_fill(const int* __restrict__ topcols, const float* __restrict__ topvals,
                       const float* __restrict__ dis, int* __restrict__ cursor,
                       int* __restrict__ csr_src, float* __restrict__ csr_w){
  int id = blockIdx.x*blockDim.x + threadIdx.x;
  if (id >= NEDGE) return;
  int n = id / (KTOP+1), e = id % (KTOP+1);
  int m; float v;
  if (e < KTOP){ m = topcols[n*KTOP+e]; v = topvals[n*KTOP+e]; }
  else { m = n; v = 1.0f; }
  if ((unsigned)m >= NN){ m = n; v = 0.0f; }   // sentinel safety
  float w = v * dis[n] * dis[m];
  int pos = atomicAdd(&cursor[m], 1);
  csr_src[pos] = n; csr_w[pos] = w;
}

// ---------------- scatter (last occurrence wins, numpy semantics) ----------------
__global__ void k_winner(const int* __restrict__ idx, int* __restrict__ winner){
  int s = blockIdx.x*blockDim.x + threadIdx.x;
  if (s >= NSUB) return;
  atomicMax(&winner[idx[s]], s);
}

__global__ void k_h0(const float* __restrict__ subset, const float* __restrict__ uinit,
                     const int* __restrict__ winner, u16* __restrict__ h){
  int id = blockIdx.x*blockDim.x + threadIdx.x;
  if (id >= ROWS*(DD/2)) return;
  int c2 = id % (DD/2); int bn = id / (DD/2); int n = bn % NN; int b = bn / NN;
  int w = winner[n];
  float2 v;
  if (w >= 0) v = *(const float2*)&subset[((size_t)b*NSUB + w)*DD + c2*2];
  else        v = *(const float2*)&uinit[c2*2];
  ((u32*)h)[id] = (u32)f2b(v.x) | ((u32)f2b(v.y) << 16);
}

// ---------------- weight transpose/convert: wbf[mat][n][k] = W[k][n] ----------------
__global__ void k_wprep(const float* __restrict__ mlp_w, const float* __restrict__ gate_w,
                        const float* __restrict__ diff_w, u16* __restrict__ wbf){
  int id = blockIdx.x*blockDim.x + threadIdx.x;
  if (id >= NLAY*5*WMAT) return;
  int mat = id / WMAT, rem = id % WMAT;
  int n = rem / DD, k = rem % DD;
  int layer = mat / 5, which = mat % 5;
  float v;
  if (which == 0)      v = mlp_w [((size_t)layer*DD   + k      )*DD + n];
  else if (which == 1) v = gate_w[((size_t)layer*2*DD + k      )*DD + n];
  else if (which == 2) v = gate_w[((size_t)layer*2*DD + DD + k )*DD + n];
  else if (which == 3) v = diff_w[((size_t)layer*2*DD + k      )*DD + n];
  else                 v = diff_w[((size_t)layer*2*DD + DD + k )*DD + n];
  wbf[id] = f2b(v);
}

// ---------------- SpMM: agg[b,m,:] = sum_in-edges w * h[b,src,:] ----------------
// thread = (8-channel group c8 0..23, batch b 0..7); one dwordx4 gather per edge.
__global__ __launch_bounds__(192) void k_spmm(const u16* __restrict__ h, const int* __restrict__ rowptr,
                       const int* __restrict__ csr_src, const float* __restrict__ csr_w,
                       u16* __restrict__ agg){
  __shared__ int s_src[128]; __shared__ float s_w[128];
  int m = blockIdx.x;
  int c8 = threadIdx.x % 24;
  int b  = threadIdx.x / 24;
  int beg = rowptr[m], end = rowptr[m+1];
  float acc[8];
  #pragma unroll
  for (int i = 0; i < 8; i++) acc[i] = 0.f;
  for (int base = beg; base < end; base += 128){
    int cnt = end - base; if (cnt > 128) cnt = 128;
    __syncthreads();
    for (int e = threadIdx.x; e < cnt; e += 192){ s_src[e] = csr_src[base+e]; s_w[e] = csr_w[base+e]; }
    __syncthreads();
    for (int e = 0; e < cnt; e++){
      int src = s_src[e]; float w = s_w[e];
      uint4 pk = *(const uint4*)&h[((size_t)b*NN + src)*DD + c8*8];
      u32 ws[4] = {pk.x, pk.y, pk.z, pk.w};
      #pragma unroll
      for (int t2 = 0; t2 < 4; t2++){
        u32 u = ws[t2];
        acc[t2*2]   += w * __uint_as_float(u << 16);
        acc[t2*2+1] += w * __uint_as_float(u & 0xffff0000u);
      }
    }
  }
  uint4 o;
  o.x = (u32)f2b(acc[0]) | ((u32)f2b(acc[1]) << 16);
  o.y = (u32)f2b(acc[2]) | ((u32)f2b(acc[3]) << 16);
  o.z = (u32)f2b(acc[4]) | ((u32)f2b(acc[5]) << 16);
  o.w = (u32)f2b(acc[6]) | ((u32)f2b(acc[7]) << 16);
  *(uint4*)&agg[((size_t)b*NN + m)*DD + c8*8] = o;
}

// ---------------- fused layer: hn / gate / highway / diffusion (bf16 MFMA) ----------------
// Wave w owns col-tiles {3w,3w+1,3w+2}; B fragments register-resident per stage.
#define LP 200  // LDS row pitch in bf16 elems (192 + 8 pad)
__global__ __launch_bounds__(256, 2) void k_layer(u16* __restrict__ h, const u16* __restrict__ agg,
                        const u16* __restrict__ wl, const float* __restrict__ mb,
                        const float* __restrict__ gb, const float* __restrict__ db){
  __shared__ u16 Ah[64*LP];
  __shared__ u16 Ax[64*LP];
  const int tid = threadIdx.x, lane = tid & 63, wave = tid >> 6;
  const int q = lane >> 4, ln = lane & 15;
  const int row0 = blockIdx.x*64;

  for (int i = tid; i < 64*24; i += 256){
    int r = i/24, c0 = i%24;
    ((uint4*)&Ah[r*LP])[c0] = ((const uint4*)h  )[(size_t)(row0+r)*24 + c0];
    ((uint4*)&Ax[r*LP])[c0] = ((const uint4*)agg)[(size_t)(row0+r)*24 + c0];
  }
  __syncthreads();

  const u16 *Wm = wl, *G1 = wl + WMAT, *G2 = wl + 2*WMAT, *D1 = wl + 3*WMAT, *D2 = wl + 4*WMAT;

  f32x4 acc[4][3];
  bf16x8 Bf[6][3];

  auto loadB = [&](const u16* wp){
    #pragma unroll
    for (int kk = 0; kk < 6; kk++)
      #pragma unroll
      for (int ntl = 0; ntl < 3; ntl++){
        int nt = wave*3 + ntl;
        Bf[kk][ntl] = *(const bf16x8*)&wp[(size_t)(nt*16 + ln)*DD + kk*32 + q*8];
      }
  };
  auto gemm = [&](const u16* Al){
    #pragma unroll
    for (int kk = 0; kk < 6; kk++){
      bf16x8 a[4];
      #pragma unroll
      for (int rt = 0; rt < 4; rt++)
        a[rt] = *(const bf16x8*)&Al[(rt*16 + ln)*LP + kk*32 + q*8];
      #pragma unroll
      for (int rt = 0; rt < 4; rt++)
        #pragma unroll
        for (int ntl = 0; ntl < 3; ntl++)
          acc[rt][ntl] = __builtin_amdgcn_mfma_f32_16x16x32_bf16(a[rt], Bf[kk][ntl], acc[rt][ntl], 0, 0, 0);
    }
  };
  auto zacc = [&](){
    #pragma unroll
    for (int rt = 0; rt < 4; rt++)
      #pragma unroll
      for (int ntl = 0; ntl < 3; ntl++)
        acc[rt][ntl] = (f32x4){0.f, 0.f, 0.f, 0.f};
  };

  // ---- stage 1: hn = agg @ Wm + mb  -> Ax
  zacc(); loadB(Wm); gemm(Ax);
  __syncthreads();
  #pragma unroll
  for (int ntl = 0; ntl < 3; ntl++){
    int col = (wave*3 + ntl)*16 + ln; float bias = mb[col];
    #pragma unroll
    for (int rt = 0; rt < 4; rt++)
      #pragma unroll
      for (int r = 0; r < 4; r++)
        Ax[(rt*16 + q*4 + r)*LP + col] = f2b(acc[rt][ntl][r] + bias);
  }
  __syncthreads();

  // ---- stage 2: g = sigmoid(h@G1 + hn@G2 + gb); lo = g*hn + (1-g)*h -> Ax
  zacc(); loadB(G1); gemm(Ah); loadB(G2); gemm(Ax);
  __syncthreads();
  #pragma unroll
  for (int ntl = 0; ntl < 3; ntl++){
    int col = (wave*3 + ntl)*16 + ln; float bias = gb[col];
    #pragma unroll
    for (int rt = 0; rt < 4; rt++)
      #pragma unroll
      for (int r = 0; r < 4; r++){
        int off = (rt*16 + q*4 + r)*LP + col;
        float g = 1.f/(1.f + expf(-(acc[rt][ntl][r] + bias)));
        float hv = b2f(Ah[off]), hnv = b2f(Ax[off]);
        Ax[off] = f2b(g*hnv + (1.f - g)*hv);
      }
  }
  __syncthreads();

  // ---- stage 3: dg = sigmoid(h@D1 + lo@D2 + db); h' = dg*lo + (1-dg)*h -> global
  zacc(); loadB(D1); gemm(Ah); loadB(D2); gemm(Ax);
  #pragma unroll
  for (int ntl = 0; ntl < 3; ntl++){
    int col = (wave*3 + ntl)*16 + ln; float bias = db[col];
    #pragma unroll
    for (int rt = 0; rt < 4; rt++)
      #pragma unroll
      for (int r = 0; r < 4; r++){
        int row = rt*16 + q*4 + r; int off = row*LP + col;
        float dg = 1.f/(1.f + expf(-(acc[rt][ntl][r] + bias)));
        float lov = b2f(Ax[off]), hv = b2f(Ah[off]);
        h[(size_t)(row0 + row)*DD + col] = f2b(dg*lov + (1.f - dg)*hv);
      }
  }
}

// ---------------- final confidence fusion (fp32 h0 path kept exact) ----------------
__global__ void k_final(const u16* __restrict__ h, const float* __restrict__ subset,
                        const int* __restrict__ winner, const float* __restrict__ ca_p,
                        float* __restrict__ out){
  int id = blockIdx.x*blockDim.x + threadIdx.x;
  if (id >= ROWS*(DD/2)) return;
  int c2 = id % (DD/2); int bn = id / (DD/2); int n = bn % NN; int b = bn / NN;
  float ca = ca_p[0];
  int w = winner[n];
  u32 hp = ((const u32*)h)[id];
  float hlo = __uint_as_float(hp << 16);
  float hhi = __uint_as_float(hp & 0xffff0000u);
  float2 o;
  if (w >= 0){
    float2 h0 = *(const float2*)&subset[((size_t)b*NSUB + w)*DD + c2*2];
    o.x = (1.0f - ca)*h0.x + ca*hlo;
    o.y = (1.0f - ca)*h0.y + ca*hhi;
  } else {
    o.x = hlo; o.y = hhi;
  }
  *(float2*)&out[(size_t)bn*DD + c2*2] = o;
}

extern "C" void kernel_launch(void* const* d_in, const int* in_sizes, int n_in,
                              void* d_out, int out_size, void* d_ws, size_t ws_size,
                              hipStream_t stream) {
  const float* subset = (const float*)d_in[0];
  const int*   idxs   = (const int*)  d_in[1];
  const float* emb1   = (const float*)d_in[2];
  const float* emb2   = (const float*)d_in[3];
  const float* l1w    = (const float*)d_in[4];
  const float* l1b    = (const float*)d_in[5];
  const float* l2w    = (const float*)d_in[6];
  const float* l2b    = (const float*)d_in[7];
  const float* uinit  = (const float*)d_in[8];
  const float* mlp_w  = (const float*)d_in[9];
  const float* mlp_b  = (const float*)d_in[10];
  const float* gate_w = (const float*)d_in[11];
  const float* gate_b = (const float*)d_in[12];
  const float* diff_w = (const float*)d_in[13];
  const float* diff_b = (const float*)d_in[14];
  const float* ca     = (const float*)d_in[15];
  float* out = (float*)d_out;

  char* base = (char*)d_ws; size_t off = 0;
  auto alloc = [&](size_t b)->void*{ void* p = base + off; off += b; off = (off + 255) & ~(size_t)255; return p; };
  u16*   Uht     = (u16*)  alloc((size_t)NN*KP*2);
  u16*   Ult     = (u16*)  alloc((size_t)NN*KP*2);
  u16*   Vht     = (u16*)  alloc((size_t)NN*KP*2);
  u16*   Vlt     = (u16*)  alloc((size_t)NN*KP*2);
  u16*   h       = (u16*)  alloc((size_t)ROWS*DD*2);
  u16*   agg     = (u16*)  alloc((size_t)ROWS*DD*2);
  u16*   wbf     = (u16*)  alloc((size_t)NLAY*5*WMAT*2);
  int*   topcols = (int*)  alloc((size_t)NN*KTOP*4);
  float* topvals = (float*)alloc((size_t)NN*KTOP*4);
  float* dis     = (float*)alloc((size_t)NN*4);
  int*   winner  = (int*)  alloc((size_t)NN*4);
  int*   counts  = (int*)  alloc((size_t)NN*4);
  int*   rowptr  = (int*)  alloc((size_t)(NN+1)*4);
  int*   cursor  = (int*)  alloc((size_t)NN*4);
  int*   csr_src = (int*)  alloc((size_t)NEDGE*4);
  float* csr_w   = (float*)alloc((size_t)NEDGE*4);
  float* ptv     = (float*)alloc((size_t)NSTRIP*RCAP*KTOP*4);
  int*   ptc     = (int*)  alloc((size_t)NSTRIP*RCAP*KTOP*4);

  // 1. graph constructor tables (f16 hi/lo, padded to 96)
  k_prep_uv<<<(NN*GD + 255)/256, 256, 0, stream>>>(emb1, emb2, l1w, l1b, l2w, l2b,
                                                   Uht, Ult, Vht, Vlt);

  // 2. fused score + top-k, then strip merge
  dim3 gs(94, NSTRIP);
  k_scoretopk<<<gs, 256, 0, stream>>>(Uht, Ult, Vht, Vlt, ptv, ptc);
  k_mergetopk<<<(NN + 255)/256, 256, 0, stream>>>(ptv, ptc, topcols, topvals, dis);

  // 3. CSR of transpose graph
  hipMemsetAsync(counts, 0, (size_t)NN*4, stream);
  k_count<<<(NEDGE + 255)/256, 256, 0, stream>>>(topcols, counts);
  k_scan<<<1, 1024, 0, stream>>>(counts, rowptr, cursor);
  k_fill<<<(NEDGE + 255)/256, 256, 0, stream>>>(topcols, topvals, dis, cursor, csr_src, csr_w);

  // 4. scatter init
  hipMemsetAsync(winner, 0xFF, (size_t)NN*4, stream);
  k_winner<<<(NSUB + 255)/256, 256, 0, stream>>>(idxs, winner);
  k_h0<<<(ROWS*(DD/2) + 255)/256, 256, 0, stream>>>(subset, uinit, winner, h);

  // 5. weights -> bf16 transposed
  k_wprep<<<(NLAY*5*WMAT + 255)/256, 256, 0, stream>>>(mlp_w, gate_w, diff_w, wbf);

  // 6. layers
  for (int l = 0; l < NLAY; l++){
    k_spmm<<<NN, 192, 0, stream>>>(h, rowptr, csr_src, csr_w, agg);
    k_layer<<<ROWS/64, 256, 0, stream>>>(h, agg, wbf + (size_t)l*5*WMAT,
                                         mlp_b + l*DD, gate_b + l*DD, diff_b + l*DD);
  }

  // 7. confidence fusion
  k_final<<<(ROWS*(DD/2) + 255)/256, 256, 0, stream>>>(h, subset, winner, ca, out);
}